// Round 2
// baseline (739.921 us; speedup 1.0000x reference)
//
#include <hip/hip_runtime.h>
#include <stdint.h>

typedef __attribute__((ext_vector_type(8))) short s8v;
typedef __attribute__((ext_vector_type(4))) float f4v;

// ---- problem geometry ----
// x:(512,260) conv1-> h:(512,64,130) conv2-> z_e:(512,128,65)=z:(512,8320)
// codebook:(8192,8320); scores s_j = ||c_j||^2 - 2 z.c_j ; argmin
// outputs: emb[1], x_hat[512*260], mt[512*16], adv[512*16], perp[1]
#define OUT_XHAT 1
#define OUT_MT   133121
#define OUT_ADV  141313
#define OUT_PERP 149505

// ---- workspace layout (float offsets) ----
// packcb/cbt are ELIMINATED: scores reads fp32 codebook directly and
// converts during LDS staging. counts/emb/a1/cn accumulators replaced by
// non-atomic partials -> only zn2 needs zeroing.
#define WS_EMBP     0            // 512   emb-loss per-row partials
#define WS_A1P      512          // 1,310,720  adv1 partials [10][512][256]
#define WS_CNP      1311232      // 16,384  cb norm partials [2][8192]
#define WS_ZN2      1327616      // 512   z row norms^2 (atomic)
#define WS_W2T      1328128      // 32768
#define WS_WE       1360896      // 16384
#define WS_WO       1377280      // 16384
#define WS_W2TA     1393664      // 32768
#define WS_IDX      1426432      // 512 ints
#define WS_ZE       1426944      // 4,259,840  z_e
#define WS_SC0      5686784      // 4,194,304  raw -2*dot (K half 0)
#define WS_SC1      9881088      // 4,194,304  raw -2*dot (K half 1)
#define WS_HD       14075392     // 4,259,840  deconv1 out
#define WS_ZPK      18335232     // 2,129,920 floats = 4,259,840 shorts
// total 20,465,152 floats (~82 MB)

__device__ __forceinline__ short f2bf(float f) {
  uint32_t u = __float_as_uint(f);
  u = (u + 0x7FFFu + ((u >> 16) & 1u)) >> 16;  // RNE truncate to bf16
  return (short)u;
}

__device__ __forceinline__ uint32_t cvtpk(float a, float b) {
  uint32_t r;
  asm("v_cvt_pk_bf16_f32 %0, %1, %2" : "=v"(r) : "v"(a), "v"(b));
  return r;  // r[15:0]=bf16(a), r[31:16]=bf16(b)
}

__device__ __forceinline__ void gl_lds16(const void* g, void* l) {
  __builtin_amdgcn_global_load_lds(
      (const __attribute__((address_space(1))) void*)g,
      (__attribute__((address_space(3))) void*)l, 16, 0, 0);
}

// ---------------- init (zn2 only) + weight prep ----------------
__global__ void k_initprep(float* __restrict__ W, const float* __restrict__ c2w,
                           const float* __restrict__ d1w,
                           const float* __restrict__ aw2) {
  int id = blockIdx.x * 256 + threadIdx.x;
  float* w2t = W + WS_W2T;
  float* We = W + WS_WE;
  float* Wo = W + WS_WO;
  float* w2ta = W + WS_W2TA;
  if (id < 512) (W + WS_ZN2)[id] = 0.f;
  if (id < 32768) {
    int c = id & 127, ik = id >> 7;
    int i = ik >> 2, k = ik & 3;
    w2t[id] = c2w[(c * 64 + i) * 4 + k];     // w2t[(i*4+k)*128+c]
    int kk = id >> 7;
    w2ta[id] = aw2[(id & 127) * 256 + kk];   // w2ta[k*128+n]
  }
  if (id < 16384) {
    int o = id & 63, is = id >> 6;
    int i = is >> 1, s = is & 1;
    We[id] = d1w[(i * 64 + o) * 4 + (3 - 2 * s)];
    Wo[id] = d1w[(i * 64 + o) * 4 + (2 - 2 * s)];
  }
}

// ---------------- conv2 with inline conv1 (bitwise-identical h) ------------
__global__ __launch_bounds__(256) void k_conv2f(
    const float* __restrict__ x, const float* __restrict__ c1w,
    const float* __restrict__ c1b, const float* __restrict__ w2t,
    const float* __restrict__ c2b, float* __restrict__ zebuf) {
  __shared__ float At[32 * 64];
  __shared__ float Bt[32 * 128];
  __shared__ float xs[520];
  __shared__ float w1s[256];
  __shared__ float b1s[64];
  int bid = blockIdx.x, tid = threadIdx.x;
  int row0 = bid * 64;
  int tm = (tid & 15) * 4;
  int tn = (tid >> 4) * 8;
  int sr = tid & 63;
  int sj0 = (tid >> 6) * 8;
  int rowm = row0 + sr;
  int gb = rowm / 65;
  int gt = rowm - gb * 65;
  int gb0 = row0 / 65;
  int xrow = gb - gb0;
  int tpos = 2 * gt - 1;
  int bkr = tid >> 3;
  int bnc = (tid & 7) * 16;
  for (int u = tid; u < 520; u += 256) {
    int rr = gb0 + (u >= 260 ? 1 : 0);
    if (rr > 511) rr = 511;
    xs[u] = x[rr * 260 + (u >= 260 ? u - 260 : u)];
  }
  if (tid < 256) w1s[tid] = c1w[tid];
  if (tid < 64) b1s[tid] = c1b[tid];
  __syncthreads();
  float acc[4][8];
#pragma unroll
  for (int i = 0; i < 4; ++i)
#pragma unroll
    for (int j = 0; j < 8; ++j) acc[i][j] = 0.f;
  for (int k0i = 0; k0i < 256; k0i += 32) {
    float av[8];
#pragma unroll
    for (int u = 0; u < 8; ++u) {
      int jj = k0i + sj0 + u;
      int cc = jj >> 2;
      int kk = jj & 3;
      int p = tpos + kk;
      float hv = 0.f;
      if (p >= 0 && p < 130) {
        float a = b1s[cc];
        int base = 2 * p - 1;
#pragma unroll
        for (int k = 0; k < 4; ++k) {
          int xp = base + k;
          float xv = (xp >= 0 && xp < 260) ? xs[xrow * 260 + xp] : 0.f;
          a = fmaf(xv, w1s[cc * 4 + k], a);
        }
        hv = fmaxf(a, 0.f);
      }
      av[u] = hv;
    }
    float bvv[16];
#pragma unroll
    for (int u = 0; u < 16; ++u) bvv[u] = w2t[(k0i + bkr) * 128 + bnc + u];
    __syncthreads();
#pragma unroll
    for (int u = 0; u < 8; ++u) At[(sj0 + u) * 64 + sr] = av[u];
#pragma unroll
    for (int u = 0; u < 16; ++u) Bt[bkr * 128 + bnc + u] = bvv[u];
    __syncthreads();
#pragma unroll
    for (int kk = 0; kk < 32; ++kk) {
      float a0 = At[kk * 64 + tm + 0];
      float a1 = At[kk * 64 + tm + 1];
      float a2 = At[kk * 64 + tm + 2];
      float a3 = At[kk * 64 + tm + 3];
#pragma unroll
      for (int j = 0; j < 8; ++j) {
        float bv = Bt[kk * 128 + tn + j];
        acc[0][j] = fmaf(a0, bv, acc[0][j]);
        acc[1][j] = fmaf(a1, bv, acc[1][j]);
        acc[2][j] = fmaf(a2, bv, acc[2][j]);
        acc[3][j] = fmaf(a3, bv, acc[3][j]);
      }
    }
  }
#pragma unroll
  for (int i = 0; i < 4; ++i) {
    int rr = row0 + tm + i;
    int b = rr / 65, t = rr - b * 65;
#pragma unroll
    for (int j = 0; j < 8; ++j) {
      int n = tn + j;
      zebuf[(size_t)b * 8320 + (size_t)n * 65 + t] = acc[i][j] + c2b[n];
    }
  }
}

// ---------------- pack z fp32 [512 x 8320] -> bf16 k-chunk-major + zn2 -----
__device__ __forceinline__ void packz_body(
    const float* __restrict__ src, short* __restrict__ dst,
    float* __restrict__ nrm2, int bid, int tid, short* tile, float* rsq) {
  int n0 = (bid % 8) * 64;
  int k0 = (bid / 8) * 64;
  int nr = tid >> 2, qc = tid & 3;
  const float* sp = src + (size_t)(n0 + nr) * 8320 + k0 + qc * 16;
  float v[16];
  *(float4*)&v[0] = *(const float4*)(sp);
  *(float4*)&v[4] = *(const float4*)(sp + 4);
  *(float4*)&v[8] = *(const float4*)(sp + 8);
  *(float4*)&v[12] = *(const float4*)(sp + 12);
  float sq = 0.f;
#pragma unroll
  for (int i = 0; i < 16; ++i) sq = fmaf(v[i], v[i], sq);
  union { short s[8]; int4 q; } u0, u1;
#pragma unroll
  for (int j = 0; j < 8; ++j) {
    u0.s[j] = f2bf(v[j]);
    u1.s[j] = f2bf(v[8 + j]);
  }
  *(int4*)&tile[((qc * 2 + 0) * 64 + nr) * 8] = u0.q;
  *(int4*)&tile[((qc * 2 + 1) * 64 + nr) * 8] = u1.q;
  rsq[tid] = sq;
  __syncthreads();
  if (tid < 64) {
    float s = rsq[tid * 4] + rsq[tid * 4 + 1] + rsq[tid * 4 + 2] + rsq[tid * 4 + 3];
    atomicAdd(&nrm2[n0 + tid], s);
  }
  int kc = tid >> 5, nn = (tid & 31) * 2;
  size_t ob = ((size_t)(k0 / 8 + kc) * 512 + n0 + nn) * 8;
  *(int4*)&dst[ob] = *(int4*)&tile[(kc * 64 + nn) * 8];
  *(int4*)&dst[ob + 8] = *(int4*)&tile[(kc * 64 + nn + 1) * 8];
}

// ---------------- megaB: adv1 ∪ mt ∪ packz (all read only z_e) -------------
// blocks [0,320): adv1 (K-split 10, non-atomic partials)
// blocks [320,832): mt   [832,1872): packz
__global__ __launch_bounds__(256) void k_megaB(
    const float* __restrict__ z_e, const float* __restrict__ mtw,
    const float* __restrict__ mtb, const float* __restrict__ aw1,
    short* __restrict__ zpk, float* __restrict__ zn2,
    float* __restrict__ a1p, float* __restrict__ out) {
  __shared__ __align__(16) char smem[16384];
  int bid = blockIdx.x, tid = threadIdx.x;
  if (bid < 320) {
    float* At = (float*)smem;
    float* Bt = At + 2048;
    int ksp = bid % 10;
    int nt = (bid / 10) & 3;
    int mt = bid / 40;
    int m0 = mt * 64, n0 = nt * 64, kb = ksp * 416;
    int tm = (tid & 15) * 4, tn = (tid >> 4) * 4;
    int sr = tid & 63, sj = (tid >> 6) * 8;
    const float* za = z_e + (size_t)(m0 + sr) * 8320 + 4160 + kb + sj;
    const float* wb = aw1 + (size_t)(n0 + sr) * 4160 + kb + sj;
    float acc[4][4];
#pragma unroll
    for (int i = 0; i < 4; ++i)
#pragma unroll
      for (int j = 0; j < 4; ++j) acc[i][j] = 0.f;
    for (int k0 = 0; k0 < 416; k0 += 32) {
      float4 av0 = *(const float4*)(za + k0);
      float4 av1 = *(const float4*)(za + k0 + 4);
      float4 bv0 = *(const float4*)(wb + k0);
      float4 bv1 = *(const float4*)(wb + k0 + 4);
      __syncthreads();
      At[(sj + 0) * 64 + sr] = av0.x; At[(sj + 1) * 64 + sr] = av0.y;
      At[(sj + 2) * 64 + sr] = av0.z; At[(sj + 3) * 64 + sr] = av0.w;
      At[(sj + 4) * 64 + sr] = av1.x; At[(sj + 5) * 64 + sr] = av1.y;
      At[(sj + 6) * 64 + sr] = av1.z; At[(sj + 7) * 64 + sr] = av1.w;
      Bt[(sj + 0) * 64 + sr] = bv0.x; Bt[(sj + 1) * 64 + sr] = bv0.y;
      Bt[(sj + 2) * 64 + sr] = bv0.z; Bt[(sj + 3) * 64 + sr] = bv0.w;
      Bt[(sj + 4) * 64 + sr] = bv1.x; Bt[(sj + 5) * 64 + sr] = bv1.y;
      Bt[(sj + 6) * 64 + sr] = bv1.z; Bt[(sj + 7) * 64 + sr] = bv1.w;
      __syncthreads();
#pragma unroll
      for (int kk = 0; kk < 32; ++kk) {
        float4 aa = *(const float4*)&At[kk * 64 + tm];
        float4 bb = *(const float4*)&Bt[kk * 64 + tn];
        acc[0][0] = fmaf(aa.x, bb.x, acc[0][0]); acc[0][1] = fmaf(aa.x, bb.y, acc[0][1]);
        acc[0][2] = fmaf(aa.x, bb.z, acc[0][2]); acc[0][3] = fmaf(aa.x, bb.w, acc[0][3]);
        acc[1][0] = fmaf(aa.y, bb.x, acc[1][0]); acc[1][1] = fmaf(aa.y, bb.y, acc[1][1]);
        acc[1][2] = fmaf(aa.y, bb.z, acc[1][2]); acc[1][3] = fmaf(aa.y, bb.w, acc[1][3]);
        acc[2][0] = fmaf(aa.z, bb.x, acc[2][0]); acc[2][1] = fmaf(aa.z, bb.y, acc[2][1]);
        acc[2][2] = fmaf(aa.z, bb.z, acc[2][2]); acc[2][3] = fmaf(aa.z, bb.w, acc[2][3]);
        acc[3][0] = fmaf(aa.w, bb.x, acc[3][0]); acc[3][1] = fmaf(aa.w, bb.y, acc[3][1]);
        acc[3][2] = fmaf(aa.w, bb.z, acc[3][2]); acc[3][3] = fmaf(aa.w, bb.w, acc[3][3]);
      }
    }
#pragma unroll
    for (int i = 0; i < 4; ++i)
#pragma unroll
      for (int j = 0; j < 4; ++j)
        a1p[((size_t)ksp * 512 + m0 + tm + i) * 256 + n0 + tn + j] = acc[i][j];
  } else if (bid < 832) {
    float* red = (float*)smem;  // 64
    int b = bid - 320;
    int wave = tid >> 6, lane = tid & 63;
    const float* zr = z_e + (size_t)b * 8320;
    float acc[16];
#pragma unroll
    for (int n = 0; n < 16; ++n) acc[n] = 0.f;
    for (int k4 = tid; k4 < 1040; k4 += 256) {
      float4 zv = *(const float4*)&zr[k4 * 4];
#pragma unroll
      for (int n = 0; n < 16; ++n) {
        float4 wv = *(const float4*)&mtw[n * 4160 + k4 * 4];
        float a = acc[n];
        a = fmaf(zv.x, wv.x, a);
        a = fmaf(zv.y, wv.y, a);
        a = fmaf(zv.z, wv.z, a);
        a = fmaf(zv.w, wv.w, a);
        acc[n] = a;
      }
    }
#pragma unroll
    for (int n = 0; n < 16; ++n) {
      float v = acc[n];
      for (int off = 32; off > 0; off >>= 1) v += __shfl_down(v, off);
      if (lane == 0) red[n * 4 + wave] = v;
    }
    __syncthreads();
    if (tid < 16) {
      float s = red[tid * 4] + red[tid * 4 + 1] + red[tid * 4 + 2] + red[tid * 4 + 3];
      out[OUT_MT + b * 16 + tid] = s + mtb[tid];
    }
  } else {
    short* tile = (short*)smem;
    float* rsq = (float*)(smem + 8192);
    packz_body(z_e, zpk, zn2, bid - 832, tid, tile, rsq);
  }
}

// ---------------- scores GEMM: A via gl_lds16(zpk), B reg-staged fp32 ------
// 128x128 tile, BK=64, Ksplit=2. mt==0 blocks also produce cn partials.
// sc holds RAW -2*dot; cn added in argmin.
__global__ __launch_bounds__(256, 2) void k_scores(
    const float* __restrict__ cb, const short* __restrict__ zpk,
    float* __restrict__ sc0, float* __restrict__ sc1,
    float* __restrict__ cnp) {
  __shared__ short As[8 * 128 * 8];  // 16 KB  [kc][m][8]
  __shared__ short Bs[8 * 128 * 8];  // 16 KB  [kc][n][8]
  int bid = blockIdx.x;
  int kh = bid & 1, nt = (bid >> 1) & 63, mt = bid >> 7;
  int tid = threadIdx.x;
  int wave = tid >> 6, lane = tid & 63;
  int q = lane >> 4, r16 = lane & 15;
  int m0 = mt * 128, n0 = nt * 128;
  int cb8 = kh * 520;
  int rb = (wave >> 1) * 64, cw = (wave & 1) * 64;
  // B staging: thread -> row n = tid>>1, k-quarter = (tid&1)*32
  int bn = tid >> 1, bkq = (tid & 1) * 32;
  const float* brow = cb + (size_t)(n0 + bn) * 8320 + kh * 4160 + bkq;
  short* bdst = &Bs[((bkq >> 3) * 128 + bn) * 8];

  f4v acc[4][4];
#pragma unroll
  for (int i = 0; i < 4; ++i)
#pragma unroll
    for (int j = 0; j < 4; ++j)
#pragma unroll
      for (int r = 0; r < 4; ++r) acc[i][j][r] = 0.f;

  float csq = 0.f;
  const float4* bp = (const float4*)brow;
  float4 f0 = bp[0], f1 = bp[1], f2 = bp[2], f3 = bp[3];
  float4 f4_ = bp[4], f5 = bp[5], f6 = bp[6], f7 = bp[7];

  for (int ks = 0; ks < 65; ++ks) {
    int c0 = cb8 + ks * 8;
    if (mt == 0) {
      csq = fmaf(f0.x, f0.x, csq); csq = fmaf(f0.y, f0.y, csq);
      csq = fmaf(f0.z, f0.z, csq); csq = fmaf(f0.w, f0.w, csq);
      csq = fmaf(f1.x, f1.x, csq); csq = fmaf(f1.y, f1.y, csq);
      csq = fmaf(f1.z, f1.z, csq); csq = fmaf(f1.w, f1.w, csq);
      csq = fmaf(f2.x, f2.x, csq); csq = fmaf(f2.y, f2.y, csq);
      csq = fmaf(f2.z, f2.z, csq); csq = fmaf(f2.w, f2.w, csq);
      csq = fmaf(f3.x, f3.x, csq); csq = fmaf(f3.y, f3.y, csq);
      csq = fmaf(f3.z, f3.z, csq); csq = fmaf(f3.w, f3.w, csq);
      csq = fmaf(f4_.x, f4_.x, csq); csq = fmaf(f4_.y, f4_.y, csq);
      csq = fmaf(f4_.z, f4_.z, csq); csq = fmaf(f4_.w, f4_.w, csq);
      csq = fmaf(f5.x, f5.x, csq); csq = fmaf(f5.y, f5.y, csq);
      csq = fmaf(f5.z, f5.z, csq); csq = fmaf(f5.w, f5.w, csq);
      csq = fmaf(f6.x, f6.x, csq); csq = fmaf(f6.y, f6.y, csq);
      csq = fmaf(f6.z, f6.z, csq); csq = fmaf(f6.w, f6.w, csq);
      csq = fmaf(f7.x, f7.x, csq); csq = fmaf(f7.y, f7.y, csq);
      csq = fmaf(f7.z, f7.z, csq); csq = fmaf(f7.w, f7.w, csq);
    }
    int4 w0, w1, w2, w3;
    w0.x = (int)cvtpk(f0.x, f0.y); w0.y = (int)cvtpk(f0.z, f0.w);
    w0.z = (int)cvtpk(f1.x, f1.y); w0.w = (int)cvtpk(f1.z, f1.w);
    w1.x = (int)cvtpk(f2.x, f2.y); w1.y = (int)cvtpk(f2.z, f2.w);
    w1.z = (int)cvtpk(f3.x, f3.y); w1.w = (int)cvtpk(f3.z, f3.w);
    w2.x = (int)cvtpk(f4_.x, f4_.y); w2.y = (int)cvtpk(f4_.z, f4_.w);
    w2.z = (int)cvtpk(f5.x, f5.y); w2.w = (int)cvtpk(f5.z, f5.w);
    w3.x = (int)cvtpk(f6.x, f6.y); w3.y = (int)cvtpk(f6.z, f6.w);
    w3.z = (int)cvtpk(f7.x, f7.y); w3.w = (int)cvtpk(f7.z, f7.w);
    __syncthreads();
#pragma unroll
    for (int i = 0; i < 4; ++i) {
      int kc = wave * 2 + (i & 1);
      int h = (i >> 1) * 64;
      size_t gk = (size_t)(c0 + kc);
      gl_lds16(zpk + (gk * 512 + m0 + h + lane) * 8, &As[(kc * 128 + h) * 8]);
    }
    *(int4*)(bdst + 0 * 128 * 8) = w0;
    *(int4*)(bdst + 1 * 128 * 8) = w1;
    *(int4*)(bdst + 2 * 128 * 8) = w2;
    *(int4*)(bdst + 3 * 128 * 8) = w3;
    __syncthreads();
    // T14: prefetch next B tile under the MFMA cluster
    if (ks < 64) {
      const float4* np = (const float4*)(brow + (ks + 1) * 64);
      f0 = np[0]; f1 = np[1]; f2 = np[2]; f3 = np[3];
      f4_ = np[4]; f5 = np[5]; f6 = np[6]; f7 = np[7];
    }
    s8v af[2][4], bfr[2][4];
#pragma unroll
    for (int g = 0; g < 2; ++g) {
      int kq = (g * 4 + q) * 128;
#pragma unroll
      for (int i = 0; i < 4; ++i) {
        af[g][i] = *(const s8v*)&As[(kq + rb + i * 16 + r16) * 8];
        bfr[g][i] = *(const s8v*)&Bs[(kq + cw + i * 16 + r16) * 8];
      }
    }
#pragma unroll
    for (int g = 0; g < 2; ++g)
#pragma unroll
      for (int mi = 0; mi < 4; ++mi)
#pragma unroll
        for (int ni = 0; ni < 4; ++ni)
          acc[mi][ni] = __builtin_amdgcn_mfma_f32_16x16x32_bf16(
              af[g][mi], bfr[g][ni], acc[mi][ni], 0, 0, 0);
  }

  if (mt == 0) {
    csq += __shfl_xor(csq, 1);
    if (!(tid & 1)) cnp[kh * 8192 + n0 + bn] = csq;
  }
  float* sc = kh ? sc1 : sc0;
#pragma unroll
  for (int mi = 0; mi < 4; ++mi) {
#pragma unroll
    for (int ni = 0; ni < 4; ++ni) {
      int col = n0 + cw + ni * 16 + r16;
#pragma unroll
      for (int r = 0; r < 4; ++r) {
        int row = m0 + rb + mi * 16 + q * 4 + r;
        sc[(size_t)row * 8192 + col] = -2.f * acc[mi][ni][r];
      }
    }
  }
}

// ---------------- argmin + exact recheck + gather/emb (fused) --------------
// srow = sc0 + sc1 + cn (cn = cnp0+cnp1). Margin is STATISTICAL:
// ||z||_2/131072 + 1e-4 (~25 sigma on bf16 score error; typical 1st-2nd
// gap ~1.6e-3). Exact fp32 recheck guards final selection.
__global__ __launch_bounds__(256) void k_argming(
    const float* __restrict__ s0, const float* __restrict__ s1,
    const float* __restrict__ z_e, const float* __restrict__ cb,
    const float* __restrict__ zn2, const float* __restrict__ cnp,
    int* __restrict__ idx, float* __restrict__ embp) {
  __shared__ float srow[8192];   // 32 KB summed scores
  __shared__ float red[256];
  __shared__ int cand[128];
  __shared__ float cval[128];
  __shared__ int ccnt;
  __shared__ int bsel;
  int b = blockIdx.x, tid = threadIdx.x;
  const float* r0 = s0 + (size_t)b * 8192;
  const float* r1 = s1 + (size_t)b * 8192;
  const float* cn0 = cnp;
  const float* cn1 = cnp + 8192;
  float mn = 1e30f;
  for (int j4 = tid; j4 < 2048; j4 += 256) {
    float4 a = *(const float4*)&r0[j4 * 4];
    float4 c = *(const float4*)&r1[j4 * 4];
    float4 n = *(const float4*)&cn0[j4 * 4];
    float4 m2 = *(const float4*)&cn1[j4 * 4];
    float4 v;
    v.x = a.x + c.x + (n.x + m2.x);
    v.y = a.y + c.y + (n.y + m2.y);
    v.z = a.z + c.z + (n.z + m2.z);
    v.w = a.w + c.w + (n.w + m2.w);
    *(float4*)&srow[j4 * 4] = v;
    mn = fminf(mn, fminf(fminf(v.x, v.y), fminf(v.z, v.w)));
  }
  red[tid] = mn;
  __syncthreads();
  for (int st = 128; st > 0; st >>= 1) {
    if (tid < st) red[tid] = fminf(red[tid], red[tid + st]);
    __syncthreads();
  }
  float minv = red[0];
  float margin = sqrtf(zn2[b]) * (1.0f / 131072.0f) + 1e-4f;
  if (tid == 0) ccnt = 0;
  __syncthreads();
  float thr = minv + margin;
  for (int j = tid; j < 8192; j += 256) {
    if (srow[j] <= thr) {
      int p = atomicAdd(&ccnt, 1);
      if (p < 128) cand[p] = j;
    }
  }
  __syncthreads();
  int nc = min(ccnt, 128);
  int wave = tid >> 6, lane = tid & 63;
  const float* zr = z_e + (size_t)b * 8320;
  float zn = zn2[b];
  for (int ci = wave; ci < nc; ci += 4) {
    int j = cand[ci];
    const float* cr = cb + (size_t)j * 8320;
    float dp = 0.f;
    for (int k4 = lane; k4 < 2080; k4 += 64) {
      float4 zv = *(const float4*)&zr[k4 * 4];
      float4 cv = *(const float4*)&cr[k4 * 4];
      dp = fmaf(zv.x, cv.x, dp);
      dp = fmaf(zv.y, cv.y, dp);
      dp = fmaf(zv.z, cv.z, dp);
      dp = fmaf(zv.w, cv.w, dp);
    }
    for (int off = 32; off > 0; off >>= 1) dp += __shfl_down(dp, off);
    // replicate reference rounding: fl(fl(zn+cn) - fl(2*dot))
    if (lane == 0) {
      float cnj = __fadd_rn(cn0[j], cn1[j]);
      cval[ci] = __fsub_rn(__fadd_rn(zn, cnj), __fmul_rn(2.f, dp));
    }
  }
  __syncthreads();
  if (tid == 0) {
    float bv = 1e30f;
    int bj = 0x7fffffff;
    for (int ci = 0; ci < nc; ++ci) {
      float v = cval[ci];
      int j = cand[ci];
      if (v < bv || (v == bv && j < bj)) { bv = v; bj = j; }
    }
    idx[b] = bj;
    bsel = bj;
  }
  __syncthreads();
  // ---- fused gather/emb partial: sum (cb[bj]-z)^2 ----
  int bj = bsel;
  const float* cr2 = cb + (size_t)bj * 8320;
  float part = 0.f;
  for (int k4 = tid; k4 < 2080; k4 += 256) {
    float4 cv = *(const float4*)&cr2[k4 * 4];
    float4 zv = *(const float4*)&zr[k4 * 4];
    float d0 = cv.x - zv.x, d1 = cv.y - zv.y;
    float d2 = cv.z - zv.z, d3 = cv.w - zv.w;
    part += d0 * d0 + d1 * d1 + d2 * d2 + d3 * d3;
  }
  red[tid] = part;
  __syncthreads();
  for (int st = 128; st > 0; st >>= 1) {
    if (tid < st) red[tid] += red[tid + st];
    __syncthreads();
  }
  if (tid == 0) embp[b] = red[0];
}

// ---------------- deconv1 (both parities; reads cb via idx) ----------------
__global__ __launch_bounds__(256) void k_dec1both(
    const float* __restrict__ cb, const int* __restrict__ idxb,
    const float* __restrict__ We, const float* __restrict__ Wo,
    const float* __restrict__ bias, float* __restrict__ hd) {
  __shared__ float At[32 * 64];
  __shared__ float Bt[32 * 64];
  int bid = blockIdx.x, tid = threadIdx.x;
  int par = (bid >= 520) ? 1 : 0;
  int bl = bid - par * 520;
  const float* wt = par ? Wo : We;
  int toff = par - 1;  // -1 even, 0 odd
  int row0 = bl * 64;
  int tm = (tid & 15) * 4, tn = (tid >> 4) * 4;
  int sr = tid & 63, sj0 = (tid >> 6) * 8;
  int rowm = row0 + sr;
  int gb = rowm / 65, gt = rowm - gb * 65;
  const float* sbase = cb + (size_t)idxb[gb] * 8320;  // zq row == codebook row
  int tpos = gt + toff;
  int bkr = tid >> 3, bnc = (tid & 7) * 8;
  float acc[4][4];
#pragma unroll
  for (int i = 0; i < 4; ++i)
#pragma unroll
    for (int j = 0; j < 4; ++j) acc[i][j] = 0.f;
  for (int k0 = 0; k0 < 256; k0 += 32) {
    float av[8];
#pragma unroll
    for (int u = 0; u < 8; ++u) {
      int jj = k0 + sj0 + u;
      int cc = jj >> 1;
      int kk = jj & 1;
      int p = tpos + kk;
      av[u] = (p >= 0 && p < 65) ? sbase[cc * 65 + p] : 0.f;
    }
    float bvv[8];
#pragma unroll
    for (int u = 0; u < 8; ++u) bvv[u] = wt[(k0 + bkr) * 64 + bnc + u];
    __syncthreads();
#pragma unroll
    for (int u = 0; u < 8; ++u) At[(sj0 + u) * 64 + sr] = av[u];
#pragma unroll
    for (int u = 0; u < 8; ++u) Bt[bkr * 64 + bnc + u] = bvv[u];
    __syncthreads();
#pragma unroll
    for (int kk = 0; kk < 32; ++kk) {
      float a0 = At[kk * 64 + tm + 0];
      float a1 = At[kk * 64 + tm + 1];
      float a2 = At[kk * 64 + tm + 2];
      float a3 = At[kk * 64 + tm + 3];
#pragma unroll
      for (int j = 0; j < 4; ++j) {
        float bv = Bt[kk * 64 + tn + j];
        acc[0][j] = fmaf(a0, bv, acc[0][j]);
        acc[1][j] = fmaf(a1, bv, acc[1][j]);
        acc[2][j] = fmaf(a2, bv, acc[2][j]);
        acc[3][j] = fmaf(a3, bv, acc[3][j]);
      }
    }
  }
#pragma unroll
  for (int i = 0; i < 4; ++i) {
    int rr = row0 + tm + i;
    int b = rr / 65, t = rr - b * 65;
#pragma unroll
    for (int j = 0; j < 4; ++j) {
      int n = tn + j;
      float v = fmaxf(acc[i][j] + bias[n], 0.f);
      hd[(size_t)b * 8320 + (size_t)n * 130 + t * 2 + par] = v;
    }
  }
}

// ---------------- megaC: dec2 ∪ adv23(partial-sum) ∪ fin(histogram) --------
// blocks [0,520): dec2   [520,1032): adv23   [1032]: fin
__global__ void k_megaC(const float* __restrict__ hd, const float* __restrict__ d2w,
                        const float* __restrict__ d2b,
                        const float* __restrict__ a1p, const float* __restrict__ b1,
                        const float* __restrict__ w2ta, const float* __restrict__ b2,
                        const float* __restrict__ w3, const float* __restrict__ b3,
                        const int* __restrict__ idxb,
                        const float* __restrict__ embp,
                        const float* __restrict__ beta_p, float* __restrict__ out) {
  __shared__ int hsh[8192];    // fin: codebook-usage histogram
  __shared__ float sbuf[384];
  int bid = blockIdx.x, tid = threadIdx.x;
  if (bid < 520) {
    int id = bid * 256 + tid;
    if (id >= 512 * 260) return;
    int b = id / 260, t = id % 260;
    int u = t >> 1;
    const float* hb = hd + (size_t)b * 8320;
    float acc = d2b[0];
    if (t & 1) {
      bool ok = (u + 1 < 130);
      for (int i = 0; i < 64; ++i) {
        acc = fmaf(hb[i * 130 + u], d2w[i * 4 + 2], acc);
        if (ok) acc = fmaf(hb[i * 130 + u + 1], d2w[i * 4 + 0], acc);
      }
    } else {
      bool ok = (u >= 1);
      for (int i = 0; i < 64; ++i) {
        if (ok) acc = fmaf(hb[i * 130 + u - 1], d2w[i * 4 + 3], acc);
        acc = fmaf(hb[i * 130 + u], d2w[i * 4 + 1], acc);
      }
    }
    out[OUT_XHAT + id] = acc;
  } else if (bid < 1032) {
    float* s1 = sbuf;        // 256
    float* s2 = sbuf + 256;  // 128
    int b = bid - 520;
    float s = b1[tid];
    const float* ap = a1p + (size_t)b * 256 + tid;
#pragma unroll
    for (int p = 0; p < 10; ++p) s += ap[(size_t)p * 131072];
    s1[tid] = fmaxf(s, 0.f);
    __syncthreads();
    if (tid < 128) {
      float acc = b2[tid];
      for (int k = 0; k < 256; ++k) acc = fmaf(s1[k], w2ta[k * 128 + tid], acc);
      s2[tid] = fmaxf(acc, 0.f);
    }
    __syncthreads();
    if (tid < 16) {
      float acc = b3[tid];
      for (int k = 0; k < 128; ++k) acc = fmaf(s2[k], w3[tid * 128 + k], acc);
      out[OUT_ADV + b * 16 + tid] = acc;
    }
  } else {
    float* red = sbuf;
    for (int j = tid; j < 8192; j += 256) hsh[j] = 0;
    __syncthreads();
    for (int i = tid; i < 512; i += 256) atomicAdd(&hsh[idxb[i]], 1);
    __syncthreads();
    float part = 0.f;
    for (int j = tid; j < 8192; j += 256) {
      float e = (float)hsh[j] * (1.0f / 512.0f);
      part += e * logf(e + 1e-10f);
    }
    float ep = 0.f;
    for (int i = tid; i < 512; i += 256) ep += embp[i];
    red[tid] = part;
    __syncthreads();
    for (int st = 128; st > 0; st >>= 1) {
      if (tid < st) red[tid] += red[tid + st];
      __syncthreads();
    }
    float negH = red[0];
    __syncthreads();
    red[tid] = ep;
    __syncthreads();
    for (int st = 128; st > 0; st >>= 1) {
      if (tid < st) red[tid] += red[tid + st];
      __syncthreads();
    }
    if (tid == 0) {
      out[OUT_PERP] = expf(-negH);
      out[0] = (1.f + beta_p[0]) * red[0] * (1.0f / 4259840.0f);
    }
  }
}

extern "C" void kernel_launch(void* const* d_in, const int* in_sizes, int n_in,
                              void* d_out, int out_size, void* d_ws, size_t ws_size,
                              hipStream_t stream) {
  (void)in_sizes; (void)n_in; (void)out_size; (void)ws_size;
  const float* x   = (const float*)d_in[0];
  const float* cb  = (const float*)d_in[1];
  const float* c1w = (const float*)d_in[2];
  const float* c1b = (const float*)d_in[3];
  const float* c2w = (const float*)d_in[4];
  const float* c2b = (const float*)d_in[5];
  const float* d1w = (const float*)d_in[6];
  const float* d1b = (const float*)d_in[7];
  const float* d2w = (const float*)d_in[8];
  const float* d2b = (const float*)d_in[9];
  const float* mtw = (const float*)d_in[10];
  const float* mtb = (const float*)d_in[11];
  const float* aw1 = (const float*)d_in[12];
  const float* ab1 = (const float*)d_in[13];
  const float* aw2 = (const float*)d_in[14];
  const float* ab2 = (const float*)d_in[15];
  const float* aw3 = (const float*)d_in[16];
  const float* ab3 = (const float*)d_in[17];
  const float* beta = (const float*)d_in[18];
  float* out = (float*)d_out;
  float* W = (float*)d_ws;

  float* embp   = W + WS_EMBP;
  float* a1p    = W + WS_A1P;
  float* cnp    = W + WS_CNP;
  float* zn2    = W + WS_ZN2;
  float* w2t    = W + WS_W2T;
  float* We     = W + WS_WE;
  float* Wo     = W + WS_WO;
  float* w2ta   = W + WS_W2TA;
  int*   idxb   = (int*)(W + WS_IDX);
  float* zebuf  = W + WS_ZE;
  float* sc0    = W + WS_SC0;
  float* sc1    = W + WS_SC1;
  float* hdbuf  = W + WS_HD;
  short* zpk    = (short*)(W + WS_ZPK);

  k_initprep<<<128, 256, 0, stream>>>(W, c2w, d1w, aw2);
  k_conv2f<<<520, 256, 0, stream>>>(x, c1w, c1b, w2t, c2b, zebuf);
  k_megaB<<<320 + 512 + 1040, 256, 0, stream>>>(zebuf, mtw, mtb, aw1,
                                                zpk, zn2, a1p, out);
  k_scores<<<512, 256, 0, stream>>>(cb, zpk, sc0, sc1, cnp);
  k_argming<<<512, 256, 0, stream>>>(sc0, sc1, zebuf, cb, zn2, cnp, idxb, embp);
  k_dec1both<<<1040, 256, 0, stream>>>(cb, idxb, We, Wo, d1b, hdbuf);
  k_megaC<<<520 + 512 + 1, 256, 0, stream>>>(hdbuf, d2w, d2b, a1p, ab1,
                                             w2ta, ab2, aw3, ab3, idxb,
                                             embp, beta, out);
}

// Round 4
// 693.942 us; speedup vs baseline: 1.0663x; 1.0663x over previous
//
#include <hip/hip_runtime.h>
#include <stdint.h>

typedef __attribute__((ext_vector_type(8))) short s8v;
typedef __attribute__((ext_vector_type(4))) float f4v;

// ---- problem geometry ----
// x:(512,260) conv1-> h:(512,64,130) conv2-> z_e:(512,128,65)=z:(512,8320)
// codebook:(8192,8320); scores s_j = ||c_j||^2 - 2 z.c_j ; argmin
// outputs: emb[1], x_hat[512*260], mt[512*16], adv[512*16], perp[1]
#define OUT_XHAT 1
#define OUT_MT   133121
#define OUT_ADV  141313
#define OUT_PERP 149505

// ---- workspace layout (float offsets) ----
// bf16 codebook pack RESTORED (R2's direct-fp32 scores was latency-bound).
// Non-atomic partials kept from R2: a1p, embp; fin uses idx histogram.
#define WS_EMBP     0            // 512   emb-loss per-row partials
#define WS_A1P      512          // 1,310,720  adv1 partials [10][512][256]
#define WS_CN       1311232      // 8192  codebook row norms^2 (atomic)
#define WS_ZN2      1319424      // 512   z row norms^2 (atomic)
#define WS_W2T      1319936      // 32768
#define WS_WE       1352704      // 16384
#define WS_WO       1369088      // 16384
#define WS_W2TA     1385472      // 32768
#define WS_IDX      1418240      // 512 ints
#define WS_ZE       1418752      // 4,259,840  z_e
#define WS_SC0      5678592      // 4,194,304  scores K-half0 (+cn)
#define WS_SC1      9872896      // 4,194,304  scores K-half1
#define WS_HD       14067200     // 4,259,840  deconv1 out
#define WS_ZPK      18327040     // 2,129,920 floats = 4,259,840 shorts
#define WS_CBT      20456960     // 34,078,720 floats = 68,157,440 shorts
// total 54,535,680 floats (~218 MB)

__device__ __forceinline__ short f2bf(float f) {
  uint32_t u = __float_as_uint(f);
  u = (u + 0x7FFFu + ((u >> 16) & 1u)) >> 16;  // RNE truncate to bf16
  return (short)u;
}

__device__ __forceinline__ void gl_lds16(const void* g, void* l) {
  __builtin_amdgcn_global_load_lds(
      (const __attribute__((address_space(1))) void*)g,
      (__attribute__((address_space(3))) void*)l, 16, 0, 0);
}

// ---------------- init (cn+zn2 only) + weight prep ----------------
__global__ void k_initprep(float* __restrict__ W, const float* __restrict__ c2w,
                           const float* __restrict__ d1w,
                           const float* __restrict__ aw2) {
  int id = blockIdx.x * 256 + threadIdx.x;
  float* w2t = W + WS_W2T;
  float* We = W + WS_WE;
  float* Wo = W + WS_WO;
  float* w2ta = W + WS_W2TA;
  if (id < 8192) (W + WS_CN)[id] = 0.f;
  if (id < 512) (W + WS_ZN2)[id] = 0.f;
  if (id < 32768) {
    int c = id & 127, ik = id >> 7;
    int i = ik >> 2, k = ik & 3;
    w2t[id] = c2w[(c * 64 + i) * 4 + k];     // w2t[(i*4+k)*128+c]
    int kk = id >> 7;
    w2ta[id] = aw2[(id & 127) * 256 + kk];   // w2ta[k*128+n]
  }
  if (id < 16384) {
    int o = id & 63, is = id >> 6;
    int i = is >> 1, s = is & 1;
    We[id] = d1w[(i * 64 + o) * 4 + (3 - 2 * s)];
    Wo[id] = d1w[(i * 64 + o) * 4 + (2 - 2 * s)];
  }
}

// ---------------- pack body: fp32 [R x 8320] -> bf16 k-chunk-major + nrm2 --
// dst[((k>>3)*R + r)*8 + (k&7)]; nrm2[r] += sum x^2
__device__ __forceinline__ void packmat_body(
    const float* __restrict__ src, short* __restrict__ dst,
    float* __restrict__ nrm2, int R, int nb, int bid, int tid,
    short* tile, float* rsq) {
  int n0 = (bid % nb) * 64;
  int k0 = (bid / nb) * 64;
  int nr = tid >> 2, qc = tid & 3;
  const float* sp = src + (size_t)(n0 + nr) * 8320 + k0 + qc * 16;
  float v[16];
  *(float4*)&v[0] = *(const float4*)(sp);
  *(float4*)&v[4] = *(const float4*)(sp + 4);
  *(float4*)&v[8] = *(const float4*)(sp + 8);
  *(float4*)&v[12] = *(const float4*)(sp + 12);
  float sq = 0.f;
#pragma unroll
  for (int i = 0; i < 16; ++i) sq = fmaf(v[i], v[i], sq);
  union { short s[8]; int4 q; } u0, u1;
#pragma unroll
  for (int j = 0; j < 8; ++j) {
    u0.s[j] = f2bf(v[j]);
    u1.s[j] = f2bf(v[8 + j]);
  }
  *(int4*)&tile[((qc * 2 + 0) * 64 + nr) * 8] = u0.q;
  *(int4*)&tile[((qc * 2 + 1) * 64 + nr) * 8] = u1.q;
  rsq[tid] = sq;
  __syncthreads();
  if (tid < 64) {
    float s = rsq[tid * 4] + rsq[tid * 4 + 1] + rsq[tid * 4 + 2] + rsq[tid * 4 + 3];
    atomicAdd(&nrm2[n0 + tid], s);
  }
  int kc = tid >> 5, nn = (tid & 31) * 2;
  size_t ob = ((size_t)(k0 / 8 + kc) * R + n0 + nn) * 8;
  *(int4*)&dst[ob] = *(int4*)&tile[(kc * 64 + nn) * 8];
  *(int4*)&dst[ob + 8] = *(int4*)&tile[(kc * 64 + nn + 1) * 8];
}

// ---------------- megaA: conv2(with inline conv1) ∪ packcb -----------------
// blocks [0,520): conv2 fused   [520,17160): pack codebook + ||c||^2
__global__ __launch_bounds__(256) void k_megaA(
    const float* __restrict__ x, const float* __restrict__ c1w,
    const float* __restrict__ c1b, const float* __restrict__ w2t,
    const float* __restrict__ c2b, float* __restrict__ zebuf,
    const float* __restrict__ cb, short* __restrict__ cbt,
    float* __restrict__ cn) {
  __shared__ __align__(16) char smem[28032];
  int bid = blockIdx.x, tid = threadIdx.x;
  if (bid < 520) {
    // ---- conv2 fused with conv1 (bitwise-identical h values) ----
    float* At = (float*)smem;        // 32*64
    float* Bt = At + 2048;           // 32*128
    float* xs = Bt + 4096;           // 2*260
    float* w1s = xs + 520;           // 256
    float* b1s = w1s + 256;          // 64
    int row0 = bid * 64;
    int tm = (tid & 15) * 4;
    int tn = (tid >> 4) * 8;
    int sr = tid & 63;
    int sj0 = (tid >> 6) * 8;
    int rowm = row0 + sr;
    int gb = rowm / 65;
    int gt = rowm - gb * 65;
    int gb0 = row0 / 65;
    int xrow = gb - gb0;
    int tpos = 2 * gt - 1;
    int bkr = tid >> 3;
    int bnc = (tid & 7) * 16;
    for (int u = tid; u < 520; u += 256) {
      int rr = gb0 + (u >= 260 ? 1 : 0);
      if (rr > 511) rr = 511;
      xs[u] = x[rr * 260 + (u >= 260 ? u - 260 : u)];
    }
    if (tid < 256) w1s[tid] = c1w[tid];
    if (tid < 64) b1s[tid] = c1b[tid];
    __syncthreads();
    float acc[4][8];
#pragma unroll
    for (int i = 0; i < 4; ++i)
#pragma unroll
      for (int j = 0; j < 8; ++j) acc[i][j] = 0.f;
    for (int k0i = 0; k0i < 256; k0i += 32) {
      float av[8];
#pragma unroll
      for (int u = 0; u < 8; ++u) {
        int jj = k0i + sj0 + u;
        int cc = jj >> 2;
        int kk = jj & 3;
        int p = tpos + kk;
        float hv = 0.f;
        if (p >= 0 && p < 130) {
          float a = b1s[cc];
          int base = 2 * p - 1;
#pragma unroll
          for (int k = 0; k < 4; ++k) {
            int xp = base + k;
            float xv = (xp >= 0 && xp < 260) ? xs[xrow * 260 + xp] : 0.f;
            a = fmaf(xv, w1s[cc * 4 + k], a);
          }
          hv = fmaxf(a, 0.f);
        }
        av[u] = hv;
      }
      float bvv[16];
#pragma unroll
      for (int u = 0; u < 16; ++u) bvv[u] = w2t[(k0i + bkr) * 128 + bnc + u];
      __syncthreads();
#pragma unroll
      for (int u = 0; u < 8; ++u) At[(sj0 + u) * 64 + sr] = av[u];
#pragma unroll
      for (int u = 0; u < 16; ++u) Bt[bkr * 128 + bnc + u] = bvv[u];
      __syncthreads();
#pragma unroll
      for (int kk = 0; kk < 32; ++kk) {
        float a0 = At[kk * 64 + tm + 0];
        float a1 = At[kk * 64 + tm + 1];
        float a2 = At[kk * 64 + tm + 2];
        float a3 = At[kk * 64 + tm + 3];
#pragma unroll
        for (int j = 0; j < 8; ++j) {
          float bv = Bt[kk * 128 + tn + j];
          acc[0][j] = fmaf(a0, bv, acc[0][j]);
          acc[1][j] = fmaf(a1, bv, acc[1][j]);
          acc[2][j] = fmaf(a2, bv, acc[2][j]);
          acc[3][j] = fmaf(a3, bv, acc[3][j]);
        }
      }
    }
#pragma unroll
    for (int i = 0; i < 4; ++i) {
      int rr = row0 + tm + i;
      int b = rr / 65, t = rr - b * 65;
#pragma unroll
      for (int j = 0; j < 8; ++j) {
        int n = tn + j;
        zebuf[(size_t)b * 8320 + (size_t)n * 65 + t] = acc[i][j] + c2b[n];
      }
    }
  } else {
    short* tile = (short*)smem;                 // 8 KB
    float* rsq = (float*)(smem + 8192);         // 1 KB
    packmat_body(cb, cbt, cn, 8192, 128, bid - 520, tid, tile, rsq);
  }
}

// ---------------- megaB: adv1 ∪ mt ∪ packz (all read only z_e) -------------
// blocks [0,320): adv1 (K-split 10, non-atomic partials)
// blocks [320,832): mt   [832,1872): packz
__global__ __launch_bounds__(256) void k_megaB(
    const float* __restrict__ z_e, const float* __restrict__ mtw,
    const float* __restrict__ mtb, const float* __restrict__ aw1,
    short* __restrict__ zpk, float* __restrict__ zn2,
    float* __restrict__ a1p, float* __restrict__ out) {
  __shared__ __align__(16) char smem[16384];
  int bid = blockIdx.x, tid = threadIdx.x;
  if (bid < 320) {
    float* At = (float*)smem;
    float* Bt = At + 2048;
    int ksp = bid % 10;
    int nt = (bid / 10) & 3;
    int mt = bid / 40;
    int m0 = mt * 64, n0 = nt * 64, kb = ksp * 416;
    int tm = (tid & 15) * 4, tn = (tid >> 4) * 4;
    int sr = tid & 63, sj = (tid >> 6) * 8;
    const float* za = z_e + (size_t)(m0 + sr) * 8320 + 4160 + kb + sj;
    const float* wb = aw1 + (size_t)(n0 + sr) * 4160 + kb + sj;
    float acc[4][4];
#pragma unroll
    for (int i = 0; i < 4; ++i)
#pragma unroll
      for (int j = 0; j < 4; ++j) acc[i][j] = 0.f;
    for (int k0 = 0; k0 < 416; k0 += 32) {
      float4 av0 = *(const float4*)(za + k0);
      float4 av1 = *(const float4*)(za + k0 + 4);
      float4 bv0 = *(const float4*)(wb + k0);
      float4 bv1 = *(const float4*)(wb + k0 + 4);
      __syncthreads();
      At[(sj + 0) * 64 + sr] = av0.x; At[(sj + 1) * 64 + sr] = av0.y;
      At[(sj + 2) * 64 + sr] = av0.z; At[(sj + 3) * 64 + sr] = av0.w;
      At[(sj + 4) * 64 + sr] = av1.x; At[(sj + 5) * 64 + sr] = av1.y;
      At[(sj + 6) * 64 + sr] = av1.z; At[(sj + 7) * 64 + sr] = av1.w;
      Bt[(sj + 0) * 64 + sr] = bv0.x; Bt[(sj + 1) * 64 + sr] = bv0.y;
      Bt[(sj + 2) * 64 + sr] = bv0.z; Bt[(sj + 3) * 64 + sr] = bv0.w;
      Bt[(sj + 4) * 64 + sr] = bv1.x; Bt[(sj + 5) * 64 + sr] = bv1.y;
      Bt[(sj + 6) * 64 + sr] = bv1.z; Bt[(sj + 7) * 64 + sr] = bv1.w;
      __syncthreads();
#pragma unroll
      for (int kk = 0; kk < 32; ++kk) {
        float4 aa = *(const float4*)&At[kk * 64 + tm];
        float4 bb = *(const float4*)&Bt[kk * 64 + tn];
        acc[0][0] = fmaf(aa.x, bb.x, acc[0][0]); acc[0][1] = fmaf(aa.x, bb.y, acc[0][1]);
        acc[0][2] = fmaf(aa.x, bb.z, acc[0][2]); acc[0][3] = fmaf(aa.x, bb.w, acc[0][3]);
        acc[1][0] = fmaf(aa.y, bb.x, acc[1][0]); acc[1][1] = fmaf(aa.y, bb.y, acc[1][1]);
        acc[1][2] = fmaf(aa.y, bb.z, acc[1][2]); acc[1][3] = fmaf(aa.y, bb.w, acc[1][3]);
        acc[2][0] = fmaf(aa.z, bb.x, acc[2][0]); acc[2][1] = fmaf(aa.z, bb.y, acc[2][1]);
        acc[2][2] = fmaf(aa.z, bb.z, acc[2][2]); acc[2][3] = fmaf(aa.z, bb.w, acc[2][3]);
        acc[3][0] = fmaf(aa.w, bb.x, acc[3][0]); acc[3][1] = fmaf(aa.w, bb.y, acc[3][1]);
        acc[3][2] = fmaf(aa.w, bb.z, acc[3][2]); acc[3][3] = fmaf(aa.w, bb.w, acc[3][3]);
      }
    }
#pragma unroll
    for (int i = 0; i < 4; ++i)
#pragma unroll
      for (int j = 0; j < 4; ++j)
        a1p[((size_t)ksp * 512 + m0 + tm + i) * 256 + n0 + tn + j] = acc[i][j];
  } else if (bid < 832) {
    float* red = (float*)smem;  // 64
    int b = bid - 320;
    int wave = tid >> 6, lane = tid & 63;
    const float* zr = z_e + (size_t)b * 8320;
    float acc[16];
#pragma unroll
    for (int n = 0; n < 16; ++n) acc[n] = 0.f;
    for (int k4 = tid; k4 < 1040; k4 += 256) {
      float4 zv = *(const float4*)&zr[k4 * 4];
#pragma unroll
      for (int n = 0; n < 16; ++n) {
        float4 wv = *(const float4*)&mtw[n * 4160 + k4 * 4];
        float a = acc[n];
        a = fmaf(zv.x, wv.x, a);
        a = fmaf(zv.y, wv.y, a);
        a = fmaf(zv.z, wv.z, a);
        a = fmaf(zv.w, wv.w, a);
        acc[n] = a;
      }
    }
#pragma unroll
    for (int n = 0; n < 16; ++n) {
      float v = acc[n];
      for (int off = 32; off > 0; off >>= 1) v += __shfl_down(v, off);
      if (lane == 0) red[n * 4 + wave] = v;
    }
    __syncthreads();
    if (tid < 16) {
      float s = red[tid * 4] + red[tid * 4 + 1] + red[tid * 4 + 2] + red[tid * 4 + 3];
      out[OUT_MT + b * 16 + tid] = s + mtb[tid];
    }
  } else {
    short* tile = (short*)smem;
    float* rsq = (float*)(smem + 8192);
    packmat_body(z_e, zpk, zn2, 512, 8, bid - 832, tid, tile, rsq);
  }
}

// ---------------- scores GEMM: m97-style, 128x128 tile, BK=64, Ksplit=2 ---
// (R1-proven version: both operands bf16 chunk-major via gl_lds16)
__global__ __launch_bounds__(256) void k_scores(const short* __restrict__ cbt,
                                                const short* __restrict__ zpk,
                                                const float* __restrict__ cn,
                                                float* __restrict__ sc0,
                                                float* __restrict__ sc1) {
  __shared__ short As[8 * 128 * 8];  // 16 KB  [kc][m][8]
  __shared__ short Bs[8 * 128 * 8];  // 16 KB  [kc][n][8]
  int bid = blockIdx.x;
  int kh = bid & 1, nt = (bid >> 1) & 63, mt = bid >> 7;
  int tid = threadIdx.x;
  int wave = tid >> 6, lane = tid & 63;
  int q = lane >> 4, r16 = lane & 15;
  int m0 = mt * 128, n0 = nt * 128;
  int cb8 = kh * 520;
  int rb = (wave >> 1) * 64, cw = (wave & 1) * 64;

  f4v acc[4][4];
#pragma unroll
  for (int i = 0; i < 4; ++i)
#pragma unroll
    for (int j = 0; j < 4; ++j)
#pragma unroll
      for (int r = 0; r < 4; ++r) acc[i][j][r] = 0.f;

  for (int ks = 0; ks < 65; ++ks) {
    int c0 = cb8 + ks * 8;
    __syncthreads();
#pragma unroll
    for (int i = 0; i < 4; ++i) {
      int kc = wave * 2 + (i & 1);
      int h = (i >> 1) * 64;
      size_t gk = (size_t)(c0 + kc);
      gl_lds16(zpk + (gk * 512 + m0 + h + lane) * 8, &As[(kc * 128 + h) * 8]);
      gl_lds16(cbt + (gk * 8192 + n0 + h + lane) * 8, &Bs[(kc * 128 + h) * 8]);
    }
    __syncthreads();
    s8v af[2][4], bfr[2][4];
#pragma unroll
    for (int g = 0; g < 2; ++g) {
      int kq = (g * 4 + q) * 128;
#pragma unroll
      for (int i = 0; i < 4; ++i) {
        af[g][i] = *(const s8v*)&As[(kq + rb + i * 16 + r16) * 8];
        bfr[g][i] = *(const s8v*)&Bs[(kq + cw + i * 16 + r16) * 8];
      }
    }
#pragma unroll
    for (int g = 0; g < 2; ++g)
#pragma unroll
      for (int mi = 0; mi < 4; ++mi)
#pragma unroll
        for (int ni = 0; ni < 4; ++ni)
          acc[mi][ni] = __builtin_amdgcn_mfma_f32_16x16x32_bf16(
              af[g][mi], bfr[g][ni], acc[mi][ni], 0, 0, 0);
  }

  float* sc = kh ? sc1 : sc0;
#pragma unroll
  for (int mi = 0; mi < 4; ++mi) {
#pragma unroll
    for (int ni = 0; ni < 4; ++ni) {
      int col = n0 + cw + ni * 16 + r16;
      float cnv = kh ? 0.f : cn[col];
#pragma unroll
      for (int r = 0; r < 4; ++r) {
        int row = m0 + rb + mi * 16 + q * 4 + r;
        sc[(size_t)row * 8192 + col] = -2.f * acc[mi][ni][r] + cnv;
      }
    }
  }
}

// ---------------- argmin + exact recheck + gather/emb (fused) --------------
// Margin is STATISTICAL: ||z||_2/131072 + 1e-4 (~25 sigma on bf16 score
// error; typical 1st-2nd gap ~1.6e-3). Exact fp32 recheck guards selection.
__global__ __launch_bounds__(256) void k_argming(
    const float* __restrict__ s0, const float* __restrict__ s1,
    const float* __restrict__ z_e, const float* __restrict__ cb,
    const float* __restrict__ zn2, const float* __restrict__ cn,
    int* __restrict__ idx, float* __restrict__ embp) {
  __shared__ float srow[8192];   // 32 KB summed scores
  __shared__ float red[256];
  __shared__ int cand[128];
  __shared__ float cval[128];
  __shared__ int ccnt;
  __shared__ int bsel;
  int b = blockIdx.x, tid = threadIdx.x;
  const float* r0 = s0 + (size_t)b * 8192;
  const float* r1 = s1 + (size_t)b * 8192;
  float mn = 1e30f;
  for (int j4 = tid; j4 < 2048; j4 += 256) {
    float4 a = *(const float4*)&r0[j4 * 4];
    float4 c = *(const float4*)&r1[j4 * 4];
    float4 v;
    v.x = a.x + c.x; v.y = a.y + c.y; v.z = a.z + c.z; v.w = a.w + c.w;
    *(float4*)&srow[j4 * 4] = v;
    mn = fminf(mn, fminf(fminf(v.x, v.y), fminf(v.z, v.w)));
  }
  red[tid] = mn;
  __syncthreads();
  for (int st = 128; st > 0; st >>= 1) {
    if (tid < st) red[tid] = fminf(red[tid], red[tid + st]);
    __syncthreads();
  }
  float minv = red[0];
  float margin = sqrtf(zn2[b]) * (1.0f / 131072.0f) + 1e-4f;
  if (tid == 0) ccnt = 0;
  __syncthreads();
  float thr = minv + margin;
  for (int j = tid; j < 8192; j += 256) {
    if (srow[j] <= thr) {
      int p = atomicAdd(&ccnt, 1);
      if (p < 128) cand[p] = j;
    }
  }
  __syncthreads();
  int nc = min(ccnt, 128);
  int wave = tid >> 6, lane = tid & 63;
  const float* zr = z_e + (size_t)b * 8320;
  float zn = zn2[b];
  for (int ci = wave; ci < nc; ci += 4) {
    int j = cand[ci];
    const float* cr = cb + (size_t)j * 8320;
    float dp = 0.f;
    for (int k4 = lane; k4 < 2080; k4 += 64) {
      float4 zv = *(const float4*)&zr[k4 * 4];
      float4 cv = *(const float4*)&cr[k4 * 4];
      dp = fmaf(zv.x, cv.x, dp);
      dp = fmaf(zv.y, cv.y, dp);
      dp = fmaf(zv.z, cv.z, dp);
      dp = fmaf(zv.w, cv.w, dp);
    }
    for (int off = 32; off > 0; off >>= 1) dp += __shfl_down(dp, off);
    // replicate reference rounding: fl(fl(zn+cn) - fl(2*dot))
    if (lane == 0)
      cval[ci] = __fsub_rn(__fadd_rn(zn, cn[j]), __fmul_rn(2.f, dp));
  }
  __syncthreads();
  if (tid == 0) {
    float bv = 1e30f;
    int bj = 0x7fffffff;
    for (int ci = 0; ci < nc; ++ci) {
      float v = cval[ci];
      int j = cand[ci];
      if (v < bv || (v == bv && j < bj)) { bv = v; bj = j; }
    }
    idx[b] = bj;
    bsel = bj;
  }
  __syncthreads();
  // ---- fused gather/emb partial: sum (cb[bj]-z)^2 ----
  int bj = bsel;
  const float* cr2 = cb + (size_t)bj * 8320;
  float part = 0.f;
  for (int k4 = tid; k4 < 2080; k4 += 256) {
    float4 cv = *(const float4*)&cr2[k4 * 4];
    float4 zv = *(const float4*)&zr[k4 * 4];
    float d0 = cv.x - zv.x, d1 = cv.y - zv.y;
    float d2 = cv.z - zv.z, d3 = cv.w - zv.w;
    part += d0 * d0 + d1 * d1 + d2 * d2 + d3 * d3;
  }
  red[tid] = part;
  __syncthreads();
  for (int st = 128; st > 0; st >>= 1) {
    if (tid < st) red[tid] += red[tid + st];
    __syncthreads();
  }
  if (tid == 0) embp[b] = red[0];
}

// ---------------- deconv1: BOTH parities in one block ----------------------
// Even/odd taps share A-data: per k-pair loads {gt-1, gt, gt+1} (3 loads,
// 4 uses). Halves block count and cuts scattered cb gather ~25%.
__global__ __launch_bounds__(256) void k_dec1both(
    const float* __restrict__ cb, const int* __restrict__ idxb,
    const float* __restrict__ We, const float* __restrict__ Wo,
    const float* __restrict__ bias, float* __restrict__ hd) {
  __shared__ float Ae[32 * 64];
  __shared__ float Ao[32 * 64];
  __shared__ float Be[32 * 64];
  __shared__ float Bo[32 * 64];
  int bid = blockIdx.x, tid = threadIdx.x;
  int row0 = bid * 64;
  int tm = (tid & 15) * 4, tn = (tid >> 4) * 4;
  int sr = tid & 63, sj0 = (tid >> 6) * 8;
  int rowm = row0 + sr;
  int gb = rowm / 65, gt = rowm - gb * 65;
  const float* sbase = cb + (size_t)idxb[gb] * 8320;  // zq row == codebook row
  int bkr = tid >> 3, bnc = (tid & 7) * 8;
  float ae[4][4], ao[4][4];
#pragma unroll
  for (int i = 0; i < 4; ++i)
#pragma unroll
    for (int j = 0; j < 4; ++j) { ae[i][j] = 0.f; ao[i][j] = 0.f; }
  for (int k0 = 0; k0 < 256; k0 += 32) {
    float ave[8], avo[8];
#pragma unroll
    for (int u = 0; u < 8; u += 2) {
      int cc = (k0 + sj0 + u) >> 1;
      const float* cp = sbase + cc * 65;
      float vm = (gt >= 1) ? cp[gt - 1] : 0.f;
      float v0 = cp[gt];
      float vp = (gt + 1 < 65) ? cp[gt + 1] : 0.f;
      ave[u] = vm; ave[u + 1] = v0;
      avo[u] = v0; avo[u + 1] = vp;
    }
    float bve[8], bvo[8];
#pragma unroll
    for (int u = 0; u < 8; ++u) {
      bve[u] = We[(k0 + bkr) * 64 + bnc + u];
      bvo[u] = Wo[(k0 + bkr) * 64 + bnc + u];
    }
    __syncthreads();
#pragma unroll
    for (int u = 0; u < 8; ++u) {
      Ae[(sj0 + u) * 64 + sr] = ave[u];
      Ao[(sj0 + u) * 64 + sr] = avo[u];
      Be[bkr * 64 + bnc + u] = bve[u];
      Bo[bkr * 64 + bnc + u] = bvo[u];
    }
    __syncthreads();
#pragma unroll
    for (int kk = 0; kk < 32; ++kk) {
      float e0 = Ae[kk * 64 + tm + 0], e1 = Ae[kk * 64 + tm + 1];
      float e2 = Ae[kk * 64 + tm + 2], e3 = Ae[kk * 64 + tm + 3];
      float o0 = Ao[kk * 64 + tm + 0], o1 = Ao[kk * 64 + tm + 1];
      float o2 = Ao[kk * 64 + tm + 2], o3 = Ao[kk * 64 + tm + 3];
#pragma unroll
      for (int j = 0; j < 4; ++j) {
        float be = Be[kk * 64 + tn + j];
        float bo = Bo[kk * 64 + tn + j];
        ae[0][j] = fmaf(e0, be, ae[0][j]);
        ae[1][j] = fmaf(e1, be, ae[1][j]);
        ae[2][j] = fmaf(e2, be, ae[2][j]);
        ae[3][j] = fmaf(e3, be, ae[3][j]);
        ao[0][j] = fmaf(o0, bo, ao[0][j]);
        ao[1][j] = fmaf(o1, bo, ao[1][j]);
        ao[2][j] = fmaf(o2, bo, ao[2][j]);
        ao[3][j] = fmaf(o3, bo, ao[3][j]);
      }
    }
  }
#pragma unroll
  for (int i = 0; i < 4; ++i) {
    int rr = row0 + tm + i;
    int b = rr / 65, t = rr - b * 65;
#pragma unroll
    for (int j = 0; j < 4; ++j) {
      int n = tn + j;
      float bn_ = bias[n];
      hd[(size_t)b * 8320 + (size_t)n * 130 + t * 2 + 0] =
          fmaxf(ae[i][j] + bn_, 0.f);
      hd[(size_t)b * 8320 + (size_t)n * 130 + t * 2 + 1] =
          fmaxf(ao[i][j] + bn_, 0.f);
    }
  }
}

// ---------------- megaC: dec2 ∪ adv23(partial-sum) ∪ fin(histogram) --------
// blocks [0,520): dec2   [520,1032): adv23   [1032]: fin
__global__ void k_megaC(const float* __restrict__ hd, const float* __restrict__ d2w,
                        const float* __restrict__ d2b,
                        const float* __restrict__ a1p, const float* __restrict__ b1,
                        const float* __restrict__ w2ta, const float* __restrict__ b2,
                        const float* __restrict__ w3, const float* __restrict__ b3,
                        const int* __restrict__ idxb,
                        const float* __restrict__ embp,
                        const float* __restrict__ beta_p, float* __restrict__ out) {
  __shared__ int hsh[8192];    // fin: codebook-usage histogram
  __shared__ float sbuf[384];
  int bid = blockIdx.x, tid = threadIdx.x;
  if (bid < 520) {
    int id = bid * 256 + tid;
    if (id >= 512 * 260) return;
    int b = id / 260, t = id % 260;
    int u = t >> 1;
    const float* hb = hd + (size_t)b * 8320;
    float acc = d2b[0];
    if (t & 1) {
      bool ok = (u + 1 < 130);
      for (int i = 0; i < 64; ++i) {
        acc = fmaf(hb[i * 130 + u], d2w[i * 4 + 2], acc);
        if (ok) acc = fmaf(hb[i * 130 + u + 1], d2w[i * 4 + 0], acc);
      }
    } else {
      bool ok = (u >= 1);
      for (int i = 0; i < 64; ++i) {
        if (ok) acc = fmaf(hb[i * 130 + u - 1], d2w[i * 4 + 3], acc);
        acc = fmaf(hb[i * 130 + u], d2w[i * 4 + 1], acc);
      }
    }
    out[OUT_XHAT + id] = acc;
  } else if (bid < 1032) {
    float* s1 = sbuf;        // 256
    float* s2 = sbuf + 256;  // 128
    int b = bid - 520;
    float s = b1[tid];
    const float* ap = a1p + (size_t)b * 256 + tid;
#pragma unroll
    for (int p = 0; p < 10; ++p) s += ap[(size_t)p * 131072];
    s1[tid] = fmaxf(s, 0.f);
    __syncthreads();
    if (tid < 128) {
      float acc = b2[tid];
      for (int k = 0; k < 256; ++k) acc = fmaf(s1[k], w2ta[k * 128 + tid], acc);
      s2[tid] = fmaxf(acc, 0.f);
    }
    __syncthreads();
    if (tid < 16) {
      float acc = b3[tid];
      for (int k = 0; k < 128; ++k) acc = fmaf(s2[k], w3[tid * 128 + k], acc);
      out[OUT_ADV + b * 16 + tid] = acc;
    }
  } else {
    float* red = sbuf;
    for (int j = tid; j < 8192; j += 256) hsh[j] = 0;
    __syncthreads();
    for (int i = tid; i < 512; i += 256) atomicAdd(&hsh[idxb[i]], 1);
    __syncthreads();
    float part = 0.f;
    for (int j = tid; j < 8192; j += 256) {
      float e = (float)hsh[j] * (1.0f / 512.0f);
      part += e * logf(e + 1e-10f);
    }
    float ep = 0.f;
    for (int i = tid; i < 512; i += 256) ep += embp[i];
    red[tid] = part;
    __syncthreads();
    for (int st = 128; st > 0; st >>= 1) {
      if (tid < st) red[tid] += red[tid + st];
      __syncthreads();
    }
    float negH = red[0];
    __syncthreads();
    red[tid] = ep;
    __syncthreads();
    for (int st = 128; st > 0; st >>= 1) {
      if (tid < st) red[tid] += red[tid + st];
      __syncthreads();
    }
    if (tid == 0) {
      out[OUT_PERP] = expf(-negH);
      out[0] = (1.f + beta_p[0]) * red[0] * (1.0f / 4259840.0f);
    }
  }
}

extern "C" void kernel_launch(void* const* d_in, const int* in_sizes, int n_in,
                              void* d_out, int out_size, void* d_ws, size_t ws_size,
                              hipStream_t stream) {
  (void)in_sizes; (void)n_in; (void)out_size; (void)ws_size;
  const float* x   = (const float*)d_in[0];
  const float* cb  = (const float*)d_in[1];
  const float* c1w = (const float*)d_in[2];
  const float* c1b = (const float*)d_in[3];
  const float* c2w = (const float*)d_in[4];
  const float* c2b = (const float*)d_in[5];
  const float* d1w = (const float*)d_in[6];
  const float* d1b = (const float*)d_in[7];
  const float* d2w = (const float*)d_in[8];
  const float* d2b = (const float*)d_in[9];
  const float* mtw = (const float*)d_in[10];
  const float* mtb = (const float*)d_in[11];
  const float* aw1 = (const float*)d_in[12];
  const float* ab1 = (const float*)d_in[13];
  const float* aw2 = (const float*)d_in[14];
  const float* ab2 = (const float*)d_in[15];
  const float* aw3 = (const float*)d_in[16];
  const float* ab3 = (const float*)d_in[17];
  const float* beta = (const float*)d_in[18];
  float* out = (float*)d_out;
  float* W = (float*)d_ws;

  float* embp   = W + WS_EMBP;
  float* a1p    = W + WS_A1P;
  float* cnbuf  = W + WS_CN;
  float* zn2    = W + WS_ZN2;
  float* w2t    = W + WS_W2T;
  float* We     = W + WS_WE;
  float* Wo     = W + WS_WO;
  float* w2ta   = W + WS_W2TA;
  int*   idxb   = (int*)(W + WS_IDX);
  float* zebuf  = W + WS_ZE;
  float* sc0    = W + WS_SC0;
  float* sc1    = W + WS_SC1;
  float* hdbuf  = W + WS_HD;
  short* zpk    = (short*)(W + WS_ZPK);
  short* cbt    = (short*)(W + WS_CBT);

  k_initprep<<<128, 256, 0, stream>>>(W, c2w, d1w, aw2);
  k_megaA<<<520 + 16640, 256, 0, stream>>>(x, c1w, c1b, w2t, c2b, zebuf,
                                           cb, cbt, cnbuf);
  k_megaB<<<320 + 512 + 1040, 256, 0, stream>>>(zebuf, mtw, mtb, aw1,
                                                zpk, zn2, a1p, out);
  k_scores<<<512, 256, 0, stream>>>(cbt, zpk, cnbuf, sc0, sc1);
  k_argming<<<512, 256, 0, stream>>>(sc0, sc1, zebuf, cb, zn2, cnbuf, idxb,
                                     embp);
  k_dec1both<<<520, 256, 0, stream>>>(cb, idxb, We, Wo, d1b, hdbuf);
  k_megaC<<<520 + 512 + 1, 256, 0, stream>>>(hdbuf, d2w, d2b, a1p, ab1,
                                             w2ta, ab2, aw3, ab3, idxb,
                                             embp, beta, out);
}